// Round 6
// baseline (250.134 us; speedup 1.0000x reference)
//
#include <hip/hip_runtime.h>
#include <hip/hip_bf16.h>
#include <math.h>

// SLAYFeatures via MFMA: out[b, h*64 + (r*32+m)] = f(proj, r), proj = x_norm . omega[r,h,:,m]
// x[B,H*D] fp32, omega[R,H,D,M] fp32. B=65536,H=16,D=64,M=32,R=2. N=R*M=64.
//
// omega lives in LDS as bf16 hi/lo planes [n][k] (XOR-swizzled), read per
// sub-tile as b128 B-frags; dot = mfma_f32_16x16x32_bf16, 3-term hi/lo split.
// Norm factored out (applied to acc in epilogue), computed fp32 from the same
// x registers that feed the A-fragments (x is read exactly once per block).
//
// Round-5 lesson: all pipes <50% at occupancy 37% -> latency-bound. Fix:
// __launch_bounds__(256,8) (VGPR<=64, LDS 16KB -> 8 blocks/CU; grid 2048 =
// 8*256CU, fully resident) + __float2bfloat16 casts so the compiler emits
// v_cvt_pk_bf16_f32 instead of ~6-op manual RNE per element.

#define HH 16
#define DD 64
#define MM 32
#define RR 2
#define NN (RR*MM)          // 64 output cols per head
#define TILE_B 512

using short8  = __attribute__((ext_vector_type(8))) short;
using floatx4 = __attribute__((ext_vector_type(4))) float;

__device__ __forceinline__ short bf16_hi(float v) {
    __hip_bfloat16 b = __float2bfloat16(v);      // RNE; pairs fuse to v_cvt_pk_bf16_f32
    return __builtin_bit_cast(short, b);
}
__device__ __forceinline__ float bf16_f(short s) {
    return __uint_as_float(((unsigned)(unsigned short)s) << 16);
}

__global__ __launch_bounds__(256, 8)
void slay_mfma_kernel(const float* __restrict__ x,
                      const float* __restrict__ omega,
                      const float* __restrict__ qn,
                      const float* __restrict__ qw,
                      float* __restrict__ out)
{
    __shared__ short lds_hi[NN * DD];   // [n][k] bf16 hi plane, swizzled (8KB)
    __shared__ short lds_lo[NN * DD];   // lo plane (8KB)

    const int tid  = threadIdx.x;
    const int lane = tid & 63;
    const int h    = blockIdx.x & (HH - 1);
    const int tile = blockIdx.x >> 4;

    const int mrow = lane & 15;    // A-row / B-col / store-col index
    const int g    = lane >> 4;    // k-group 0..3

    // ---- stage omega[.,h,.,.] -> LDS bf16 hi/lo planes [n=r*32+m][k=d] ----
    #pragma unroll
    for (int i = 0; i < (RR * DD * MM) / 256; ++i) {
        int e  = i * 256 + tid;
        int rr = e >> 11;
        int d  = (e >> 5) & (DD - 1);
        int m  = e & (MM - 1);
        float v = omega[((size_t)(rr * HH + h) * DD + d) * MM + m];
        short hi = bf16_hi(v);
        short lo = bf16_hi(v - bf16_f(hi));
        int n   = rr * MM + m;
        int byt = (d * 2) ^ ((n & 7) << 4);           // XOR swizzle within 128B row
        *(short*)((char*)lds_hi + n * (DD * 2) + byt) = hi;
        *(short*)((char*)lds_lo + n * (DD * 2) + byt) = lo;
    }
    __syncthreads();

    // quadrature scalars (uniform)
    const float sn[2]  = { qn[0], qn[1] };
    const float s2s[2] = { sqrtf(2.f * fmaxf(sn[0], 0.f)), sqrtf(2.f * fmaxf(sn[1], 0.f)) };
    const float cr[2]  = { sqrtf(fmaxf(qw[0], 0.f)) * (1.f / MM),
                           sqrtf(fmaxf(qw[1], 0.f)) * (1.f / MM) };

    const int sw = (mrow & 7) << 4;   // B-frag swizzle (row n = nt*16+mrow, n&7 == mrow&7)

    for (int st = 0; st < TILE_B / 64; ++st) {
        const int b_base = tile * TILE_B + st * 64 + (tid >> 6) * 16;
        const float* xr = x + (size_t)(b_base + mrow) * (HH * DD) + h * DD;

        // ---- load 16 x values: cols kc*32 + g*8 + {0..7} ----
        float xv[16];
        *(float4*)(xv + 0)  = *(const float4*)(xr + g * 8);
        *(float4*)(xv + 4)  = *(const float4*)(xr + g * 8 + 4);
        *(float4*)(xv + 8)  = *(const float4*)(xr + 32 + g * 8);
        *(float4*)(xv + 12) = *(const float4*)(xr + 32 + g * 8 + 4);

        // ---- fp32 row norm (sum split across the 4 k-groups) ----
        float ss = 0.f;
        #pragma unroll
        for (int j = 0; j < 16; ++j) ss = fmaf(xv[j], xv[j], ss);
        ss += __shfl_xor(ss, 16, 64);
        ss += __shfl_xor(ss, 32, 64);
        const float rnorm = 1.0f / fmaxf(sqrtf(ss), 1e-6f);

        // ---- bf16 hi/lo A-fragments (raw x; norm applied in epilogue) ----
        short8 a_hi[2], a_lo[2];
        #pragma unroll
        for (int kc = 0; kc < 2; ++kc)
            #pragma unroll
            for (int j = 0; j < 8; ++j) {
                float v  = xv[kc * 8 + j];
                short hi = bf16_hi(v);
                a_hi[kc][j] = hi;
                a_lo[kc][j] = bf16_hi(v - bf16_f(hi));
            }

        // rnorm for the 4 rows this lane's acc covers (row = g*4+q)
        float rn[4];
        #pragma unroll
        for (int q = 0; q < 4; ++q) rn[q] = __shfl(rnorm, g * 4 + q, 64);

        #pragma unroll
        for (int nt = 0; nt < 4; ++nt) {
            const char* rh = (const char*)lds_hi + (nt * 16 + mrow) * (DD * 2);
            const char* rl = (const char*)lds_lo + (nt * 16 + mrow) * (DD * 2);
            const int k0 = (g * 16) ^ sw;
            const int k1 = (64 + g * 16) ^ sw;
            short8 bh0 = *(const short8*)(rh + k0);
            short8 bh1 = *(const short8*)(rh + k1);
            short8 bl0 = *(const short8*)(rl + k0);
            short8 bl1 = *(const short8*)(rl + k1);

            floatx4 acc = {0.f, 0.f, 0.f, 0.f};
            acc = __builtin_amdgcn_mfma_f32_16x16x32_bf16(a_hi[0], bh0, acc, 0, 0, 0);
            acc = __builtin_amdgcn_mfma_f32_16x16x32_bf16(a_hi[1], bh1, acc, 0, 0, 0);
            acc = __builtin_amdgcn_mfma_f32_16x16x32_bf16(a_lo[0], bh0, acc, 0, 0, 0);
            acc = __builtin_amdgcn_mfma_f32_16x16x32_bf16(a_lo[1], bh1, acc, 0, 0, 0);
            acc = __builtin_amdgcn_mfma_f32_16x16x32_bf16(a_hi[0], bl0, acc, 0, 0, 0);
            acc = __builtin_amdgcn_mfma_f32_16x16x32_bf16(a_hi[1], bl1, acc, 0, 0, 0);

            const int r = nt >> 1;
            #pragma unroll
            for (int q = 0; q < 4; ++q) {
                float proj = acc[q] * rn[q];
                float ea = fmaf(proj, s2s[r], -sn[r]);
                ea = fminf(fmaxf(ea, -10.f), 10.f);
                float res = proj * proj * __expf(ea) * cr[r];
                int brow = b_base + g * 4 + q;
                __builtin_nontemporal_store(
                    res, out + (size_t)brow * (HH * NN) + h * NN + nt * 16 + mrow);
            }
        }
    }
}

extern "C" void kernel_launch(void* const* d_in, const int* in_sizes, int n_in,
                              void* d_out, int out_size, void* d_ws, size_t ws_size,
                              hipStream_t stream) {
    const float* x     = (const float*)d_in[0];
    const float* omega = (const float*)d_in[1];
    const float* qn    = (const float*)d_in[2];
    const float* qw    = (const float*)d_in[3];
    float* out = (float*)d_out;

    const int B = in_sizes[0] / (HH * DD);     // 65536
    dim3 grid((B / TILE_B) * HH);              // 2048 blocks; h = bid & 15
    dim3 block(256);

    slay_mfma_kernel<<<grid, block, 0, stream>>>(x, omega, qn, qw, out);
}

// Round 7
// 218.798 us; speedup vs baseline: 1.1432x; 1.1432x over previous
//
#include <hip/hip_runtime.h>
#include <hip/hip_bf16.h>
#include <math.h>

// SLAYFeatures via MFMA: out[b, h*64 + n] = f(proj, r), n = r*32+m,
// proj = x_norm . omega[r,h,:,m].  x[B,H*D] fp32, omega[R,H,D,M] fp32.
// B=65536,H=16,D=64,M=32,R=2. N=R*M=64.
//
// omega lives in LDS as bf16 hi/lo planes [n][k] (XOR-swizzled), read per
// sub-tile as b128 frags; dot = mfma_f32_16x16x32_bf16, 3-term hi/lo split.
// Operand roles: omega = A, x = B  -> D[n][b] with lane&15 = b. Each lane's
// acc[0..3] = 4 consecutive n columns of ONE row b -> float4 stores, and the
// per-lane rnorm (row = lane&15) is directly the one needed (no shfl gather).
//
// Round-6 lesson: __launch_bounds__(256,8) capped VGPR at 64 and the
// allocator overshot to 32, re-sinking x loads (FETCH 131->519MB, 2.4x dur).
// Use (256,6): 85-VGPR cap (headroom over the ~64 needed), 6 blocks/CU.

#define HH 16
#define DD 64
#define MM 32
#define RR 2
#define NN (RR*MM)          // 64 output cols per head
#define TILE_B 512

using short8  = __attribute__((ext_vector_type(8))) short;
using floatx4 = __attribute__((ext_vector_type(4))) float;

__device__ __forceinline__ short bf16_hi(float v) {
    __hip_bfloat16 b = __float2bfloat16(v);      // RNE; pairs fuse to v_cvt_pk_bf16_f32
    return __builtin_bit_cast(short, b);
}
__device__ __forceinline__ float bf16_f(short s) {
    return __uint_as_float(((unsigned)(unsigned short)s) << 16);
}

__global__ __launch_bounds__(256, 6)
void slay_mfma_kernel(const float* __restrict__ x,
                      const float* __restrict__ omega,
                      const float* __restrict__ qn,
                      const float* __restrict__ qw,
                      float* __restrict__ out)
{
    __shared__ short lds_hi[NN * DD];   // [n][k] bf16 hi plane, swizzled (8KB)
    __shared__ short lds_lo[NN * DD];   // lo plane (8KB)

    const int tid  = threadIdx.x;
    const int lane = tid & 63;
    const int h    = blockIdx.x & (HH - 1);
    const int tile = blockIdx.x >> 4;

    const int mrow = lane & 15;    // b-row index within wave tile / D col
    const int g    = lane >> 4;    // k-group 0..3

    // ---- stage omega[.,h,.,.] -> LDS bf16 hi/lo planes [n=r*32+m][k=d] ----
    #pragma unroll
    for (int i = 0; i < (RR * DD * MM) / 256; ++i) {
        int e  = i * 256 + tid;
        int rr = e >> 11;
        int d  = (e >> 5) & (DD - 1);
        int m  = e & (MM - 1);
        float v = omega[((size_t)(rr * HH + h) * DD + d) * MM + m];
        short hi = bf16_hi(v);
        short lo = bf16_hi(v - bf16_f(hi));
        int n   = rr * MM + m;
        int byt = (d * 2) ^ ((n & 7) << 4);           // XOR swizzle within 128B row
        *(short*)((char*)lds_hi + n * (DD * 2) + byt) = hi;
        *(short*)((char*)lds_lo + n * (DD * 2) + byt) = lo;
    }
    __syncthreads();

    // quadrature scalars (uniform)
    const float sn[2]  = { qn[0], qn[1] };
    const float s2s[2] = { sqrtf(2.f * fmaxf(sn[0], 0.f)), sqrtf(2.f * fmaxf(sn[1], 0.f)) };
    const float cr[2]  = { sqrtf(fmaxf(qw[0], 0.f)) * (1.f / MM),
                           sqrtf(fmaxf(qw[1], 0.f)) * (1.f / MM) };

    const int sw = (mrow & 7) << 4;   // frag swizzle (LDS row n = nt*16+mrow, n&7 == mrow&7)

    for (int st = 0; st < TILE_B / 64; ++st) {
        const int b_base = tile * TILE_B + st * 64 + (tid >> 6) * 16;
        const float* xr = x + (size_t)(b_base + mrow) * (HH * DD) + h * DD;

        // ---- load 16 x values: k = kc*32 + g*8 + {0..7} ----
        float xv[16];
        *(float4*)(xv + 0)  = *(const float4*)(xr + g * 8);
        *(float4*)(xv + 4)  = *(const float4*)(xr + g * 8 + 4);
        *(float4*)(xv + 8)  = *(const float4*)(xr + 32 + g * 8);
        *(float4*)(xv + 12) = *(const float4*)(xr + 32 + g * 8 + 4);

        // ---- fp32 row norm (sum split across the 4 k-groups) ----
        float ss = 0.f;
        #pragma unroll
        for (int j = 0; j < 16; ++j) ss = fmaf(xv[j], xv[j], ss);
        ss += __shfl_xor(ss, 16, 64);
        ss += __shfl_xor(ss, 32, 64);
        const float rnorm = 1.0f / fmaxf(sqrtf(ss), 1e-6f);  // row (b_base+mrow)'s 1/||x||

        // ---- bf16 hi/lo x fragments (B operand; raw x, norm in epilogue) ----
        short8 x_hi[2], x_lo[2];
        #pragma unroll
        for (int kc = 0; kc < 2; ++kc)
            #pragma unroll
            for (int j = 0; j < 8; ++j) {
                float v  = xv[kc * 8 + j];
                short hi = bf16_hi(v);
                x_hi[kc][j] = hi;
                x_lo[kc][j] = bf16_hi(v - bf16_f(hi));
            }

        #pragma unroll
        for (int nt = 0; nt < 4; ++nt) {
            const char* rh = (const char*)lds_hi + (nt * 16 + mrow) * (DD * 2);
            const char* rl = (const char*)lds_lo + (nt * 16 + mrow) * (DD * 2);
            const int k0 = (g * 16) ^ sw;
            const int k1 = (64 + g * 16) ^ sw;
            short8 oh0 = *(const short8*)(rh + k0);   // omega A-frag, hi plane
            short8 oh1 = *(const short8*)(rh + k1);
            short8 ol0 = *(const short8*)(rl + k0);   // lo plane
            short8 ol1 = *(const short8*)(rl + k1);

            floatx4 acc = {0.f, 0.f, 0.f, 0.f};
            acc = __builtin_amdgcn_mfma_f32_16x16x32_bf16(oh0, x_hi[0], acc, 0, 0, 0);
            acc = __builtin_amdgcn_mfma_f32_16x16x32_bf16(oh1, x_hi[1], acc, 0, 0, 0);
            acc = __builtin_amdgcn_mfma_f32_16x16x32_bf16(oh0, x_lo[0], acc, 0, 0, 0);
            acc = __builtin_amdgcn_mfma_f32_16x16x32_bf16(oh1, x_lo[1], acc, 0, 0, 0);
            acc = __builtin_amdgcn_mfma_f32_16x16x32_bf16(ol0, x_hi[0], acc, 0, 0, 0);
            acc = __builtin_amdgcn_mfma_f32_16x16x32_bf16(ol1, x_hi[1], acc, 0, 0, 0);

            // D[n][b]: this lane holds n = nt*16 + g*4 + q for row b = b_base+mrow
            const int r = nt >> 1;
            floatx4 res;
            #pragma unroll
            for (int q = 0; q < 4; ++q) {
                float proj = acc[q] * rnorm;
                float ea = fmaf(proj, s2s[r], -sn[r]);
                ea = fminf(fmaxf(ea, -10.f), 10.f);
                res[q] = proj * proj * __expf(ea) * cr[r];
            }
            floatx4* op = (floatx4*)(out + (size_t)(b_base + mrow) * (HH * NN)
                                         + h * NN + nt * 16 + g * 4);
            __builtin_nontemporal_store(res, op);
        }
    }
}

extern "C" void kernel_launch(void* const* d_in, const int* in_sizes, int n_in,
                              void* d_out, int out_size, void* d_ws, size_t ws_size,
                              hipStream_t stream) {
    const float* x     = (const float*)d_in[0];
    const float* omega = (const float*)d_in[1];
    const float* qn    = (const float*)d_in[2];
    const float* qw    = (const float*)d_in[3];
    float* out = (float*)d_out;

    const int B = in_sizes[0] / (HH * DD);     // 65536
    dim3 grid((B / TILE_B) * HH);              // 2048 blocks; h = bid & 15
    dim3 block(256);

    slay_mfma_kernel<<<grid, block, 0, stream>>>(x, omega, qn, qw, out);
}

// Round 8
// 111.418 us; speedup vs baseline: 2.2450x; 1.9638x over previous
//
#include <hip/hip_runtime.h>
#include <hip/hip_bf16.h>
#include <math.h>

// SLAYFeatures via MFMA: out[b, h*64 + n] = f(proj, r), n = r*32+m,
// proj = x_norm . omega[r,h,:,m].  x[B,H*D] fp32, omega[R,H,D,M] fp32.
// B=65536,H=16,D=64,M=32,R=2. N=R*M=64.
//
// omega in LDS as bf16 hi/lo planes [n][k] (XOR-swizzled), b128 frags;
// dot = mfma_f32_16x16x32_bf16 with 3-term hi/lo split (fp32-level accuracy).
// Operand roles: omega=A, x=B -> lane's acc[0..3] = 4 consecutive n of ONE
// row b -> float4 stores; per-lane rnorm is directly the right one.
//
// Lessons: (256,8)/(256,6) caps make the allocator sink the x loads
// (VGPR 32/40, FETCH 2.5-4x, dur 2x). (256,4) keeps them. Stay at (256,4)
// and fix latency with MANUAL PREFETCH: double-buffered xv[2][16], st-loop
// fully unrolled so indices are static (no scratch), st+1 loads issued
// before st's compute -> ~900cyc HBM latency hidden under cvt+MFMA+epilogue.

#define HH 16
#define DD 64
#define MM 32
#define RR 2
#define NN (RR*MM)          // 64 output cols per head
#define TILE_B 512
#define NST (TILE_B/64)     // 8 sub-tiles

using short8  = __attribute__((ext_vector_type(8))) short;
using floatx4 = __attribute__((ext_vector_type(4))) float;

__device__ __forceinline__ short bf16_hi(float v) {
    __hip_bfloat16 b = __float2bfloat16(v);      // RNE; pairs fuse to v_cvt_pk_bf16_f32
    return __builtin_bit_cast(short, b);
}
__device__ __forceinline__ float bf16_f(short s) {
    return __uint_as_float(((unsigned)(unsigned short)s) << 16);
}

__global__ __launch_bounds__(256, 4)
void slay_mfma_kernel(const float* __restrict__ x,
                      const float* __restrict__ omega,
                      const float* __restrict__ qn,
                      const float* __restrict__ qw,
                      float* __restrict__ out)
{
    __shared__ short lds_hi[NN * DD];   // [n][k] bf16 hi plane, swizzled (8KB)
    __shared__ short lds_lo[NN * DD];   // lo plane (8KB)

    const int tid  = threadIdx.x;
    const int lane = tid & 63;
    const int wv   = tid >> 6;
    const int h    = blockIdx.x & (HH - 1);
    const int tile = blockIdx.x >> 4;

    const int mrow = lane & 15;    // b-row index within wave tile
    const int g    = lane >> 4;    // k-group 0..3

    // ---- stage omega[.,h,.,.] -> LDS bf16 hi/lo planes [n=r*32+m][k=d] ----
    #pragma unroll
    for (int i = 0; i < (RR * DD * MM) / 256; ++i) {
        int e  = i * 256 + tid;
        int rr = e >> 11;
        int d  = (e >> 5) & (DD - 1);
        int m  = e & (MM - 1);
        float v = omega[((size_t)(rr * HH + h) * DD + d) * MM + m];
        short hi = bf16_hi(v);
        short lo = bf16_hi(v - bf16_f(hi));
        int n   = rr * MM + m;
        int byt = (d * 2) ^ ((n & 7) << 4);           // XOR swizzle within 128B row
        *(short*)((char*)lds_hi + n * (DD * 2) + byt) = hi;
        *(short*)((char*)lds_lo + n * (DD * 2) + byt) = lo;
    }
    __syncthreads();

    // quadrature scalars (uniform)
    const float sn[2]  = { qn[0], qn[1] };
    const float s2s[2] = { sqrtf(2.f * fmaxf(sn[0], 0.f)), sqrtf(2.f * fmaxf(sn[1], 0.f)) };
    const float cr[2]  = { sqrtf(fmaxf(qw[0], 0.f)) * (1.f / MM),
                           sqrtf(fmaxf(qw[1], 0.f)) * (1.f / MM) };

    const int sw = (mrow & 7) << 4;   // frag swizzle (LDS row n = nt*16+mrow)

    const float* xr0 = x + (size_t)(tile * TILE_B + wv * 16 + mrow) * (HH * DD) + h * DD;

    float xv[2][16];

    // prologue: load st=0
    *(float4*)(xv[0] + 0)  = *(const float4*)(xr0 + g * 8);
    *(float4*)(xv[0] + 4)  = *(const float4*)(xr0 + g * 8 + 4);
    *(float4*)(xv[0] + 8)  = *(const float4*)(xr0 + 32 + g * 8);
    *(float4*)(xv[0] + 12) = *(const float4*)(xr0 + 32 + g * 8 + 4);

    #pragma unroll
    for (int st = 0; st < NST; ++st) {
        const int cur = st & 1;

        // ---- prefetch st+1's x row slice (hidden under this st's compute) ----
        if (st + 1 < NST) {
            const float* xr = xr0 + (size_t)(st + 1) * 64 * (HH * DD);
            *(float4*)(xv[cur ^ 1] + 0)  = *(const float4*)(xr + g * 8);
            *(float4*)(xv[cur ^ 1] + 4)  = *(const float4*)(xr + g * 8 + 4);
            *(float4*)(xv[cur ^ 1] + 8)  = *(const float4*)(xr + 32 + g * 8);
            *(float4*)(xv[cur ^ 1] + 12) = *(const float4*)(xr + 32 + g * 8 + 4);
        }

        const int b_base = tile * TILE_B + st * 64 + wv * 16;

        // ---- fp32 row norm (sum split across the 4 k-groups) ----
        float ss = 0.f;
        #pragma unroll
        for (int j = 0; j < 16; ++j) ss = fmaf(xv[cur][j], xv[cur][j], ss);
        ss += __shfl_xor(ss, 16, 64);
        ss += __shfl_xor(ss, 32, 64);
        const float rnorm = 1.0f / fmaxf(sqrtf(ss), 1e-6f);  // row (b_base+mrow)

        // ---- bf16 hi/lo x fragments (B operand; raw x, norm in epilogue) ----
        short8 x_hi[2], x_lo[2];
        #pragma unroll
        for (int kc = 0; kc < 2; ++kc)
            #pragma unroll
            for (int j = 0; j < 8; ++j) {
                float v  = xv[cur][kc * 8 + j];
                short hi = bf16_hi(v);
                x_hi[kc][j] = hi;
                x_lo[kc][j] = bf16_hi(v - bf16_f(hi));
            }

        #pragma unroll
        for (int nt = 0; nt < 4; ++nt) {
            const char* rh = (const char*)lds_hi + (nt * 16 + mrow) * (DD * 2);
            const char* rl = (const char*)lds_lo + (nt * 16 + mrow) * (DD * 2);
            const int k0 = (g * 16) ^ sw;
            const int k1 = (64 + g * 16) ^ sw;
            short8 oh0 = *(const short8*)(rh + k0);   // omega A-frag, hi plane
            short8 oh1 = *(const short8*)(rh + k1);
            short8 ol0 = *(const short8*)(rl + k0);   // lo plane
            short8 ol1 = *(const short8*)(rl + k1);

            floatx4 acc = {0.f, 0.f, 0.f, 0.f};
            acc = __builtin_amdgcn_mfma_f32_16x16x32_bf16(oh0, x_hi[0], acc, 0, 0, 0);
            acc = __builtin_amdgcn_mfma_f32_16x16x32_bf16(oh1, x_hi[1], acc, 0, 0, 0);
            acc = __builtin_amdgcn_mfma_f32_16x16x32_bf16(oh0, x_lo[0], acc, 0, 0, 0);
            acc = __builtin_amdgcn_mfma_f32_16x16x32_bf16(oh1, x_lo[1], acc, 0, 0, 0);
            acc = __builtin_amdgcn_mfma_f32_16x16x32_bf16(ol0, x_hi[0], acc, 0, 0, 0);
            acc = __builtin_amdgcn_mfma_f32_16x16x32_bf16(ol1, x_hi[1], acc, 0, 0, 0);

            // D[n][b]: lane holds n = nt*16 + g*4 + q for row b = b_base+mrow
            const int r = nt >> 1;
            floatx4 res;
            #pragma unroll
            for (int q = 0; q < 4; ++q) {
                float proj = acc[q] * rnorm;
                float ea = fmaf(proj, s2s[r], -sn[r]);
                ea = fminf(fmaxf(ea, -10.f), 10.f);
                res[q] = proj * proj * __expf(ea) * cr[r];
            }
            floatx4* op = (floatx4*)(out + (size_t)(b_base + mrow) * (HH * NN)
                                         + h * NN + nt * 16 + g * 4);
            __builtin_nontemporal_store(res, op);
        }
    }
}

extern "C" void kernel_launch(void* const* d_in, const int* in_sizes, int n_in,
                              void* d_out, int out_size, void* d_ws, size_t ws_size,
                              hipStream_t stream) {
    const float* x     = (const float*)d_in[0];
    const float* omega = (const float*)d_in[1];
    const float* qn    = (const float*)d_in[2];
    const float* qw    = (const float*)d_in[3];
    float* out = (float*)d_out;

    const int B = in_sizes[0] / (HH * DD);     // 65536
    dim3 grid((B / TILE_B) * HH);              // 2048 blocks; h = bid & 15
    dim3 block(256);

    slay_mfma_kernel<<<grid, block, 0, stream>>>(x, omega, qn, qw, out);
}